// Round 3
// baseline (3411.715 us; speedup 1.0000x reference)
//
#include <hip/hip_runtime.h>
#include <stdint.h>
#include <math.h>

#define B_SZ 1024
#define NV   4096
#define NH   4096
#define NSGN 2048

typedef short bf16x8 __attribute__((ext_vector_type(8)));
typedef short bf16x4 __attribute__((ext_vector_type(4)));
typedef float f32x4  __attribute__((ext_vector_type(4)));

// ---------------- threefry2x32 (JAX-compatible, 20 rounds) ----------------
__host__ __device__ __forceinline__ void tf2x32(uint32_t k0, uint32_t k1,
                                                uint32_t x0, uint32_t x1,
                                                uint32_t& o0, uint32_t& o1)
{
    uint32_t k2 = k0 ^ k1 ^ 0x1BD11BDAu;
#define TFR(r) { x0 += x1; x1 = (x1 << (r)) | (x1 >> (32 - (r))); x1 ^= x0; }
    x0 += k0; x1 += k1;
    TFR(13) TFR(15) TFR(26) TFR(6)
    x0 += k1; x1 += k2 + 1u;
    TFR(17) TFR(29) TFR(16) TFR(24)
    x0 += k2; x1 += k0 + 2u;
    TFR(13) TFR(15) TFR(26) TFR(6)
    x0 += k0; x1 += k1 + 3u;
    TFR(17) TFR(29) TFR(16) TFR(24)
    x0 += k1; x1 += k2 + 4u;
    TFR(13) TFR(15) TFR(26) TFR(6)
    x0 += k2; x1 += k0 + 5u;
#undef TFR
    o0 = x0; o1 = x1;
}

__device__ __forceinline__ float tf_uniform01(uint32_t k0, uint32_t k1, uint32_t idx)
{
    uint32_t a, b;
    tf2x32(k0, k1, 0u, idx, a, b);
    uint32_t bits = a ^ b;
    uint32_t fb = (bits >> 9) | 0x3F800000u;
    return __uint_as_float(fb) - 1.0f;
}

__device__ __forceinline__ float sigmoidf_(float x)
{
    if (x >= 0.0f) { float e = expf(-x); return 1.0f / (1.0f + e); }
    float e = expf(x); return e / (1.0f + e);
}

__device__ __forceinline__ short f2bf_trunc(float f)
{
    return (short)(__float_as_uint(f) >> 16);
}
__device__ __forceinline__ float bf2f(short s)
{
    return __uint_as_float(((uint32_t)(uint16_t)s) << 16);
}

__device__ __forceinline__ void gl16(const void* g, void* l)
{
    __builtin_amdgcn_global_load_lds((const __attribute__((address_space(1))) void*)g,
                                     (__attribute__((address_space(3))) void*)l, 16, 0, 0);
}

// ---------------- weight precompute: fp32 -> hi/lo bf16 (trunc split) ----------------
__global__ __launch_bounds__(256) void conv_bt(const float* __restrict__ W,
                                               short* __restrict__ Wh, short* __restrict__ Wl)
{
    size_t i = ((size_t)blockIdx.x * 256 + threadIdx.x) * 4;
    f32x4 v = *(const f32x4*)(W + i);
    short h[4], l[4];
#pragma unroll
    for (int c = 0; c < 4; ++c) {
        uint32_t u = __float_as_uint(v[c]);
        h[c] = (short)(u >> 16);
        float hf = __uint_as_float(u & 0xFFFF0000u);
        l[c] = f2bf_trunc(v[c] - hf);
    }
    *(bf16x4*)(Wh + i) = *(bf16x4*)h;
    *(bf16x4*)(Wl + i) = *(bf16x4*)l;
}

// =====================================================================
// Fused GEMM + sampling epilogue.
//  MODE 0: K=4096, B in bt layout [n][k] (gload_lds direct)
//  MODE 1: K=8192 concat: first 4096 bt (A0,BH0), second 4096 bn (A1,BH1 as [k][n])
//  MODE 2: K=4096, B in bn layout [k][n] (reg-transpose staging)
//  EPI  0: p=sigmoid(acc+bias[col]); bern -> O0
//  EPI  1: same, dual write O0,O1
//  EPI  2: sign sampling (odd cols bern, even cols = occ), write O0 (vneg)
// tile 64(M) x 128(N), 256 threads = 4 waves (32x64 each), grid (32,16)
// =====================================================================
template<int EPI, int MODE>
__global__ __launch_bounds__(256) void mm_fast(
    const short* __restrict__ A0, const short* __restrict__ A1,
    const short* __restrict__ BH0, const short* __restrict__ BL0,
    const short* __restrict__ BH1, const short* __restrict__ BL1,
    const float* __restrict__ bias, const float* __restrict__ occ,
    short* __restrict__ O0, short* __restrict__ O1,
    uint32_t rk0, uint32_t rk1)
{
    __shared__ __align__(1024) short As[64 * 32];
    __shared__ __align__(1024) short Bhs[128 * 32];
    __shared__ __align__(1024) short Bls[128 * 32];

    const int tid = threadIdx.x;
    const int bn = blockIdx.x * 128, bm = blockIdx.y * 64;
    const int wv = tid >> 6, lane = tid & 63;
    const int wr = (wv >> 1) * 32, wc = (wv & 1) * 64;
    const int l15 = lane & 15, l4 = lane >> 4;
    const int trk = (tid >> 5) * 4, trn = (tid & 31) * 4;

    f32x4 acc[2][4] = {};
    const int KTOT = (MODE == 1) ? 8192 : 4096;

    for (int k0 = 0; k0 < KTOT; k0 += 32) {
        const bool second = (MODE == 1) && (k0 >= 4096);
        const int kk = k0 & 4095;
        const short* A  = second ? A1 : A0;
        const short* BH = second ? BH1 : BH0;
        const short* BL = second ? BL1 : BL0;
        const bool bt = (MODE == 0) || (MODE == 1 && !second);

        if (bt) {
#pragma unroll
            for (int c = 0; c < 5; ++c) {
                int blk = wv * 5 + c;
                const short* src; short* dst;
                if (blk < 4) {
                    int row = blk * 16 + (lane >> 2);
                    src = A + (size_t)(bm + row) * 4096 + kk + (lane & 3) * 8;
                    dst = &As[blk * 512];
                } else if (blk < 12) {
                    int b2 = blk - 4, row = (blk - 4) * 16 + (lane >> 2);
                    src = BH + (size_t)(bn + row) * 4096 + kk + (lane & 3) * 8;
                    dst = &Bhs[b2 * 512];
                } else {
                    int b2 = blk - 12, row = (blk - 12) * 16 + (lane >> 2);
                    src = BL + (size_t)(bn + row) * 4096 + kk + (lane & 3) * 8;
                    dst = &Bls[b2 * 512];
                }
                gl16(src, dst);
            }
        } else {
            {
                int row = wv * 16 + (lane >> 2);
                gl16(A + (size_t)(bm + row) * 4096 + kk + (lane & 3) * 8, &As[wv * 512]);
            }
            short th[4][4], tl[4][4];
#pragma unroll
            for (int i = 0; i < 4; ++i) {
                *(bf16x4*)th[i] = *(const bf16x4*)(BH + (size_t)(kk + trk + i) * 4096 + bn + trn);
                *(bf16x4*)tl[i] = *(const bf16x4*)(BL + (size_t)(kk + trk + i) * 4096 + bn + trn);
            }
#pragma unroll
            for (int j = 0; j < 4; ++j) {
                short wh[4] = {th[0][j], th[1][j], th[2][j], th[3][j]};
                short wl[4] = {tl[0][j], tl[1][j], tl[2][j], tl[3][j]};
                *(bf16x4*)&Bhs[(trn + j) * 32 + trk] = *(bf16x4*)wh;
                *(bf16x4*)&Bls[(trn + j) * 32 + trk] = *(bf16x4*)wl;
            }
        }
        __syncthreads();

        bf16x8 af[2], bhf[4], blf[4];
#pragma unroll
        for (int m = 0; m < 2; ++m)
            af[m] = *(bf16x8*)&As[(wr + m * 16 + l15) * 32 + l4 * 8];
#pragma unroll
        for (int n = 0; n < 4; ++n) {
            bhf[n] = *(bf16x8*)&Bhs[(wc + n * 16 + l15) * 32 + l4 * 8];
            blf[n] = *(bf16x8*)&Bls[(wc + n * 16 + l15) * 32 + l4 * 8];
        }
#pragma unroll
        for (int m = 0; m < 2; ++m)
#pragma unroll
            for (int n = 0; n < 4; ++n) {
                acc[m][n] = __builtin_amdgcn_mfma_f32_16x16x32_bf16(af[m], bhf[n], acc[m][n], 0, 0, 0);
                acc[m][n] = __builtin_amdgcn_mfma_f32_16x16x32_bf16(af[m], blf[n], acc[m][n], 0, 0, 0);
            }
        __syncthreads();
    }

    // ---- fused sampling epilogue ----
#pragma unroll
    for (int m = 0; m < 2; ++m)
#pragma unroll
        for (int n = 0; n < 4; ++n)
#pragma unroll
            for (int r = 0; r < 4; ++r) {
                int row = bm + wr + m * 16 + l4 * 4 + r;
                int col = bn + wc + n * 16 + l15;
                float val = acc[m][n][r];
                if (EPI == 2) {
                    if (col & 1) {
                        int s = (col - 1) >> 1;
                        uint32_t e = (uint32_t)(row * 2048 + s);
                        float p = sigmoidf_(val + bias[col]);
                        float u = tf_uniform01(rk0, rk1, e);
                        O0[(size_t)row * 4096 + col] = (u < p) ? (short)0x3F80 : (short)0;
                    } else {
                        O0[(size_t)row * 4096 + col] =
                            (occ[(size_t)row * 2048 + (col >> 1)] != 0.0f) ? (short)0x3F80 : (short)0;
                    }
                } else {
                    size_t e = (size_t)row * 4096 + col;
                    float p = sigmoidf_(val + bias[col]);
                    float u = tf_uniform01(rk0, rk1, (uint32_t)e);
                    short sv = (u < p) ? (short)0x3F80 : (short)0;
                    O0[e] = sv;
                    if (EPI == 1) O1[e] = sv;
                }
            }
}

// =====================================================================
// Gradient GEMMs (unchanged from round 2 — exact integer sums / 1024)
// =====================================================================
template<int W1MODE>
__global__ __launch_bounds__(256) void grad_mm(
    const short* __restrict__ Xn, const short* __restrict__ Yn,
    const short* __restrict__ Xp, const short* __restrict__ Yp_bf,
    const float* __restrict__ Yp_f32,
    float* __restrict__ Out)
{
    __shared__ short Xs[2][128][40];
    __shared__ short Ys[2][128][40];

    const int tid = threadIdx.x;
    const int bi = blockIdx.y * 128, bj = blockIdx.x * 128;
    const int wv = tid >> 6, lane = tid & 63;
    const int wr = (wv >> 1) * 64, wc = (wv & 1) * 64;
    const int l15 = lane & 15, l4 = lane >> 4;

    const int bb = tid & 7, ib = tid >> 3;

    f32x4 acc[4][4] = {};
    bf16x4 xr[4];
    short  yr[4][4];

    auto loadT = [&](int bt) {
        const bool neg = bt < 32;
        const int b0 = (bt & 31) * 32;
        const short* X = neg ? Xn : Xp;
#pragma unroll
        for (int r = 0; r < 4; ++r)
            xr[r] = *(const bf16x4*)(X + (size_t)(b0 + bb * 4 + r) * NH + bi + ib * 4);
        if (W1MODE) {
            if (neg) {
#pragma unroll
                for (int r = 0; r < 4; ++r) {
                    bf16x8 v = *(const bf16x8*)(Yn + (size_t)(b0 + bb * 4 + r) * NV + 2 * (bj + ib * 4));
#pragma unroll
                    for (int c = 0; c < 4; ++c) yr[r][c] = v[2 * c + 1];
                }
            } else {
#pragma unroll
                for (int r = 0; r < 4; ++r) {
                    const float* p = Yp_f32 + (size_t)(b0 + bb * 4 + r) * NV + 2 * (bj + ib * 4);
                    f32x4 a = *(const f32x4*)p;
                    f32x4 b = *(const f32x4*)(p + 4);
                    yr[r][0] = f2bf_trunc(-a[1]); yr[r][1] = f2bf_trunc(-a[3]);
                    yr[r][2] = f2bf_trunc(-b[1]); yr[r][3] = f2bf_trunc(-b[3]);
                }
            }
        } else {
            const short* Y = neg ? Yn : Yp_bf;
            const short sx = neg ? (short)0 : (short)0x8000;
#pragma unroll
            for (int r = 0; r < 4; ++r) {
                bf16x4 v = *(const bf16x4*)(Y + (size_t)(b0 + bb * 4 + r) * NH + bj + ib * 4);
#pragma unroll
                for (int c = 0; c < 4; ++c) yr[r][c] = (short)(v[c] ^ sx);
            }
        }
    };
    auto writeT = [&](int buf) {
#pragma unroll
        for (int c = 0; c < 4; ++c) {
            short w[4] = {xr[0][c], xr[1][c], xr[2][c], xr[3][c]};
            *(bf16x4*)&Xs[buf][ib * 4 + c][bb * 4] = *(bf16x4*)w;
            short y[4] = {yr[0][c], yr[1][c], yr[2][c], yr[3][c]};
            *(bf16x4*)&Ys[buf][ib * 4 + c][bb * 4] = *(bf16x4*)y;
        }
    };

    loadT(0);
    writeT(0);
    __syncthreads();

    for (int bt = 0; bt < 64; ++bt) {
        const int cur = bt & 1;
        if (bt + 1 < 64) loadT(bt + 1);

        bf16x8 xf[4], yf[4];
#pragma unroll
        for (int m = 0; m < 4; ++m)
            xf[m] = *(bf16x8*)&Xs[cur][wr + m * 16 + l15][l4 * 8];
#pragma unroll
        for (int n = 0; n < 4; ++n)
            yf[n] = *(bf16x8*)&Ys[cur][wc + n * 16 + l15][l4 * 8];
#pragma unroll
        for (int m = 0; m < 4; ++m)
#pragma unroll
            for (int n = 0; n < 4; ++n)
                acc[m][n] = __builtin_amdgcn_mfma_f32_16x16x32_bf16(xf[m], yf[n], acc[m][n], 0, 0, 0);

        if (bt + 1 < 64) writeT(cur ^ 1);
        __syncthreads();
    }

    const float invB = 1.0f / 1024.0f;
#pragma unroll
    for (int m = 0; m < 4; ++m)
#pragma unroll
        for (int n = 0; n < 4; ++n)
#pragma unroll
            for (int r = 0; r < 4; ++r) {
                int i_ = bi + wr + m * 16 + l4 * 4 + r;
                int j_ = bj + wc + n * 16 + l15;
                if (W1MODE) {
                    Out[(size_t)i_ * NV + 2 * j_ + 1] = acc[m][n][r] * invB;
                    Out[(size_t)i_ * NV + 2 * j_]     = 0.0f;
                } else {
                    Out[(size_t)i_ * NH + j_] = acc[m][n][r] * invB;
                }
            }
}

// ---------------- small kernels ----------------
__global__ void cvt_kernel(const float* __restrict__ in, short* __restrict__ out, int n)
{
    int e = blockIdx.x * 256 + threadIdx.x;
    if (e < n) out[e] = (in[e] != 0.0f) ? (short)0x3F80 : (short)0;
}

// -db_v (32 blocks, coalesced, LDS combine)
__global__ void dbv_fast(const float* __restrict__ vdata, const short* __restrict__ vneg,
                         float* __restrict__ out)
{
    __shared__ float part[4][64];
    int c = threadIdx.x & 63, rg = threadIdx.x >> 6;
    int s = blockIdx.x * 64 + c;
    float acc = 0.0f;
    for (int b = rg; b < B_SZ; b += 4)
        acc += bf2f(vneg[(size_t)b * NV + 2 * s + 1]) - vdata[(size_t)b * NV + 2 * s + 1];
    part[rg][c] = acc;
    __syncthreads();
    if (rg == 0) {
        out[2 * s + 1] = (part[0][c] + part[1][c] + part[2][c] + part[3][c]) * (1.0f / 1024.0f);
        out[2 * s] = 0.0f;
    }
}

// -db_h (64 blocks, coalesced, LDS combine)
__global__ void dbh_fast(const short* __restrict__ Xp, const short* __restrict__ Xn,
                         float* __restrict__ out)
{
    __shared__ int part[4][64];
    int c = threadIdx.x & 63, rg = threadIdx.x >> 6;
    int j = blockIdx.x * 64 + c;
    int acc = 0;
    for (int b = rg; b < B_SZ; b += 4)
        acc += (int)(Xn[(size_t)b * NH + j] != 0) - (int)(Xp[(size_t)b * NH + j] != 0);
    part[rg][c] = acc;
    __syncthreads();
    if (rg == 0)
        out[j] = (float)(part[0][c] + part[1][c] + part[2][c] + part[3][c]) * (1.0f / 1024.0f);
}

__global__ void zero_kernel(unsigned* p) { *p = 0u; }

// loss mismatch count: wave shuffle reduce + one atomic per block (1024 blocks)
__global__ void loss_count2(const float* __restrict__ vdata,
                            const short* __restrict__ vneg, unsigned* cnt)
{
    __shared__ int part[4];
    int t = blockIdx.x * 256 + threadIdx.x;
    int local = 0;
#pragma unroll
    for (int it = 0; it < 8; ++it) {
        int e = t + it * 262144;
        int b = e >> 11, s = e & 2047;
        float st = vdata[(size_t)b * NV + 2 * s + 1];
        float sp = bf2f(vneg[(size_t)b * NV + 2 * s + 1]);
        local += (st != sp) ? 1 : 0;
    }
#pragma unroll
    for (int off = 32; off; off >>= 1) local += __shfl_down(local, off, 64);
    if ((threadIdx.x & 63) == 0) part[threadIdx.x >> 6] = local;
    __syncthreads();
    if (threadIdx.x == 0)
        atomicAdd(cnt, (unsigned)(part[0] + part[1] + part[2] + part[3]));
}

__global__ void loss_final_kernel(const unsigned* cnt, float* out, float lp, float lm)
{
    float mis = (float)(*cnt);
    float mat = 2097152.0f - mis;
    out[0] = -((mat * lp + mis * lm) * (1.0f / 2097152.0f));
}

// ---------------- host ----------------
extern "C" void kernel_launch(void* const* d_in, const int* in_sizes, int n_in,
                              void* d_out, int out_size, void* d_ws, size_t ws_size,
                              hipStream_t stream)
{
    (void)in_sizes; (void)n_in; (void)out_size; (void)ws_size;
    const float* v_data = (const float*)d_in[0];
    const float* occ    = (const float*)d_in[1];
    const float* W1     = (const float*)d_in[2];
    const float* b_v    = (const float*)d_in[3];
    const float* b_h1   = (const float*)d_in[4];
    const float* b_h2   = (const float*)d_in[5];
    // NOTE: input order per setup_inputs: v_data, occupant_data, W1, b_v, b_h1, W2, b_h2, k
    const float* W2     = (const float*)d_in[5];
    b_h2                = (const float*)d_in[6];

    float* out = (float*)d_out;

    // ws: bf16 state matrices only (42 MB)
    char* w = (char*)d_ws;
    short* vneg = (short*)w;
    short* h1d  = vneg + (size_t)B_SZ * NV;
    short* h2d  = h1d  + (size_t)B_SZ * NH;
    short* h1c  = h2d  + (size_t)B_SZ * NH;
    short* h2n  = h1c  + (size_t)B_SZ * NH;
    unsigned* cnt = (unsigned*)(h2n + (size_t)B_SZ * NH);

    // d_out doubles as weight scratch during the forward phase (fully
    // overwritten by gradient kernels afterwards; deterministic per replay).
    short* W1h = (short*)(((uintptr_t)(out + 1) + 15) & ~(uintptr_t)15);
    short* W1l = W1h + (size_t)NH * NV;
    short* W2h = W1l + (size_t)NH * NV;
    short* W2l = W2h + (size_t)NH * NH;

    // ---- JAX key derivation (host, partitionable/fold-like semantics) ----
    const uint32_t r0 = 0u, r1 = 42u;
    uint32_t kp1a, kp1b, kp2a, kp2b, kfa, kfb, kla, klb;
    tf2x32(r0, r1, 0u, 0u, kp1a, kp1b);
    tf2x32(r0, r1, 0u, 1u, kp2a, kp2b);
    tf2x32(r0, r1, 0u, 2u, kfa, kfb);
    tf2x32(r0, r1, 0u, 3u, kla, klb);
    uint32_t kaA[2], kaB[2], kbA[2], kbB[2], kcA[2], kcB[2];
    for (int i = 0; i < 2; ++i) {
        uint32_t fa, fb;
        tf2x32(kla, klb, 0u, (uint32_t)i, fa, fb);
        tf2x32(fa, fb, 0u, 0u, kaA[i], kaB[i]);
        tf2x32(fa, fb, 0u, 1u, kbA[i], kbB[i]);
        tf2x32(fa, fb, 0u, 2u, kcA[i], kcB[i]);
    }

    const int T = 256;
    const int NELEM = B_SZ * NH;
    dim3 gMM(NV / 128, B_SZ / 64);     // 32 x 16 = 512 blocks

    // weight split precompute (into d_out scratch)
    conv_bt<<<(NH * NV) / (4 * 256), 256, 0, stream>>>(W1, W1h, W1l);
    conv_bt<<<(NH * NH) / (4 * 256), 256, 0, stream>>>(W2, W2h, W2l);

    cvt_kernel<<<NELEM / T, T, 0, stream>>>(v_data, vneg, NELEM);

    // positive phase: h1_data = bern(kpos1, sigmoid(v@W1^T + b_h1))   [h2 = 0]
    mm_fast<0, 0><<<gMM, 256, 0, stream>>>(vneg, nullptr, W1h, W1l, nullptr, nullptr,
                                           b_h1, nullptr, h1d, nullptr, kp1a, kp1b);
    // h2_data = bern(kpos2, sigmoid(h1@W2^T + b_h2)); dual-write h2d, h2n
    mm_fast<1, 0><<<gMM, 256, 0, stream>>>(h1d, nullptr, W2h, W2l, nullptr, nullptr,
                                           b_h2, nullptr, h2d, h2n, kp2a, kp2b);

    // Gibbs loop (k = 2)
    for (int i = 0; i < 2; ++i) {
        // h1 = bern(sigmoid(vneg@W1^T + h2n@W2 + b_h1)) — concat K=8192
        mm_fast<0, 1><<<gMM, 256, 0, stream>>>(vneg, h2n, W1h, W1l, W2h, W2l,
                                               b_h1, nullptr, h1c, nullptr, kaA[i], kaB[i]);
        // h2n = bern(sigmoid(h1c@W2^T + b_h2))
        mm_fast<0, 0><<<gMM, 256, 0, stream>>>(h1c, nullptr, W2h, W2l, nullptr, nullptr,
                                               b_h2, nullptr, h2n, nullptr, kbA[i], kbB[i]);
        // pv = sigmoid(h1c@W1 + b_v); sign-sample odd cols, occ even cols
        mm_fast<2, 2><<<gMM, 256, 0, stream>>>(h1c, nullptr, W1h, W1l, nullptr, nullptr,
                                               b_v, occ, vneg, nullptr, kcA[i], kcB[i]);
    }

    // final: h1_neg_final = bern(kfin, sigmoid(vneg@W1^T + h2n@W2 + b_h1))
    mm_fast<0, 1><<<gMM, 256, 0, stream>>>(vneg, h2n, W1h, W1l, W2h, W2l,
                                           b_h1, nullptr, h1c, nullptr, kfa, kfb);

    // outputs (weights in d_out no longer needed past this point)
    float* dW1o  = out + 1;
    float* dbvo  = dW1o + (size_t)NH * NV;
    float* dbh1o = dbvo + NV;
    float* dW2o  = dbh1o + NH;
    float* dbh2o = dW2o + (size_t)NH * NH;

    grad_mm<1><<<dim3(NSGN / 128, NH / 128), T, 0, stream>>>(h1c, vneg, h1d, (short*)nullptr, v_data, dW1o);
    grad_mm<0><<<dim3(NH / 128, NH / 128), T, 0, stream>>>(h1c, h2n, h1d, h2d, (const float*)nullptr, dW2o);
    dbv_fast<<<NSGN / 64, T, 0, stream>>>(v_data, vneg, dbvo);
    dbh_fast<<<NH / 64, T, 0, stream>>>(h1d, h1c, dbh1o);
    dbh_fast<<<NH / 64, T, 0, stream>>>(h2d, h2n, dbh2o);

    zero_kernel<<<1, 1, 0, stream>>>(cnt);
    loss_count2<<<1024, T, 0, stream>>>(v_data, vneg, cnt);
    loss_final_kernel<<<1, 1, 0, stream>>>(cnt, out, logf(1.0f + 1e-7f), logf(1e-7f));
}

// Round 4
// 2378.148 us; speedup vs baseline: 1.4346x; 1.4346x over previous
//
#include <hip/hip_runtime.h>
#include <stdint.h>
#include <math.h>

#define B_SZ 1024
#define NV   4096
#define NH   4096
#define NSGN 2048

typedef short bf16x8 __attribute__((ext_vector_type(8)));
typedef short bf16x4 __attribute__((ext_vector_type(4)));
typedef float f32x4  __attribute__((ext_vector_type(4)));

// ---------------- threefry2x32 (JAX-compatible, 20 rounds) ----------------
__host__ __device__ __forceinline__ void tf2x32(uint32_t k0, uint32_t k1,
                                                uint32_t x0, uint32_t x1,
                                                uint32_t& o0, uint32_t& o1)
{
    uint32_t k2 = k0 ^ k1 ^ 0x1BD11BDAu;
#define TFR(r) { x0 += x1; x1 = (x1 << (r)) | (x1 >> (32 - (r))); x1 ^= x0; }
    x0 += k0; x1 += k1;
    TFR(13) TFR(15) TFR(26) TFR(6)
    x0 += k1; x1 += k2 + 1u;
    TFR(17) TFR(29) TFR(16) TFR(24)
    x0 += k2; x1 += k0 + 2u;
    TFR(13) TFR(15) TFR(26) TFR(6)
    x0 += k0; x1 += k1 + 3u;
    TFR(17) TFR(29) TFR(16) TFR(24)
    x0 += k1; x1 += k2 + 4u;
    TFR(13) TFR(15) TFR(26) TFR(6)
    x0 += k2; x1 += k0 + 5u;
#undef TFR
    o0 = x0; o1 = x1;
}

__device__ __forceinline__ float tf_uniform01(uint32_t k0, uint32_t k1, uint32_t idx)
{
    uint32_t a, b;
    tf2x32(k0, k1, 0u, idx, a, b);
    uint32_t bits = a ^ b;
    uint32_t fb = (bits >> 9) | 0x3F800000u;
    return __uint_as_float(fb) - 1.0f;
}

__device__ __forceinline__ float sigmoidf_(float x)
{
    if (x >= 0.0f) { float e = expf(-x); return 1.0f / (1.0f + e); }
    float e = expf(x); return e / (1.0f + e);
}

__device__ __forceinline__ short f2bf_trunc(float f)
{
    return (short)(__float_as_uint(f) >> 16);
}
__device__ __forceinline__ float bf2f(short s)
{
    return __uint_as_float(((uint32_t)(uint16_t)s) << 16);
}

__device__ __forceinline__ void gl16(const void* g, void* l)
{
    __builtin_amdgcn_global_load_lds((const __attribute__((address_space(1))) void*)g,
                                     (__attribute__((address_space(3))) void*)l, 16, 0, 0);
}

// ---------------- weight precompute: fp32 -> hi/lo bf16 (trunc split) ----------------
__global__ __launch_bounds__(256) void conv_bt(const float* __restrict__ W,
                                               short* __restrict__ Wh, short* __restrict__ Wl)
{
    size_t i = ((size_t)blockIdx.x * 256 + threadIdx.x) * 4;
    f32x4 v = *(const f32x4*)(W + i);
    short h[4], l[4];
#pragma unroll
    for (int c = 0; c < 4; ++c) {
        uint32_t u = __float_as_uint(v[c]);
        h[c] = (short)(u >> 16);
        float hf = __uint_as_float(u & 0xFFFF0000u);
        l[c] = f2bf_trunc(v[c] - hf);
    }
    *(bf16x4*)(Wh + i) = *(bf16x4*)h;
    *(bf16x4*)(Wl + i) = *(bf16x4*)l;
}

// =====================================================================
// Fused GEMM + sampling epilogue. LDS subtiles (16 rows x 32 k = 512 shorts)
// stored in MFMA-fragment order: slot L (byte L*16) = (row L&15, kchunk L>>4).
//  bt staging: global_load_lds, per-lane source in fragment order -> linear dst.
//  bn staging: reg transpose, subtile-XOR swizzle (r ^ subtile) on write AND read.
//  MODE 0: K=4096, W [n][k].  MODE 1: K=8192 concat (bt then bn).
//  MODE 2: K=4096, W [k][n].
//  EPI 0: bern -> O0.  EPI 1: dual write.  EPI 2: sign sampling (vneg).
// tile 64(M) x 128(N), 256 threads = 4 waves (32x64 each), grid (32,16)
// =====================================================================
template<int EPI, int MODE>
__global__ __launch_bounds__(256) void mm_fast(
    const short* __restrict__ A0, const short* __restrict__ A1,
    const short* __restrict__ BH0, const short* __restrict__ BL0,
    const short* __restrict__ BH1, const short* __restrict__ BL1,
    const float* __restrict__ bias, const float* __restrict__ occ,
    short* __restrict__ O0, short* __restrict__ O1,
    uint32_t rk0, uint32_t rk1)
{
    __shared__ __align__(1024) short As[4 * 512];
    __shared__ __align__(1024) short Bhs[8 * 512];
    __shared__ __align__(1024) short Bls[8 * 512];

    const int tid = threadIdx.x;
    const int bn = blockIdx.x * 128, bm = blockIdx.y * 64;
    const int wv = tid >> 6, lane = tid & 63;
    const int wr = (wv >> 1) * 32, wc = (wv & 1) * 64;
    const int l15 = lane & 15, l4 = lane >> 4;

    // bt staging: fragment-order per-lane source
    const int fr = lane & 15;          // row within subtile
    const int fc = (lane >> 4) * 8;    // k-chunk start

    // bn staging: thread -> 4 cols x 4 k
    const int cg = (tid & 31) * 4;     // col base (0..124)
    const int kg = tid >> 5;           // k-group (0..7), k = kg*4..+3
    const int qsub = (tid & 31) >> 2;  // subtile for all 4 cols
    const int koff = (kg >> 1) * 128 + (kg & 1) * 4;  // shorts

    f32x4 acc[2][4] = {};
    const int KTOT = (MODE == 1) ? 8192 : 4096;

    for (int k0 = 0; k0 < KTOT; k0 += 32) {
        const bool second = (MODE == 1) && (k0 >= 4096);
        const int kk = k0 & 4095;
        const bool btm = (MODE == 0) || (MODE == 1 && !second);

        if (btm) {
            const short* A  = A0;
            const short* BH = BH0;
            const short* BL = BL0;
#pragma unroll
            for (int c = 0; c < 5; ++c) {
                int u = wv * 5 + c;
                if (u < 4) {
                    gl16(A + (size_t)(bm + u * 16 + fr) * 4096 + kk + fc, &As[u * 512]);
                } else if (u < 12) {
                    int s = u - 4;
                    gl16(BH + (size_t)(bn + s * 16 + fr) * 4096 + kk + fc, &Bhs[s * 512]);
                } else {
                    int s = u - 12;
                    gl16(BL + (size_t)(bn + s * 16 + fr) * 4096 + kk + fc, &Bls[s * 512]);
                }
            }
        } else {
            const short* A  = (MODE == 1) ? A1 : A0;
            const short* BH = (MODE == 1) ? BH1 : BH0;
            const short* BL = (MODE == 1) ? BL1 : BL0;
            gl16(A + (size_t)(bm + wv * 16 + fr) * 4096 + kk + fc, &As[wv * 512]);
            short th[4][4], tl[4][4];
#pragma unroll
            for (int i = 0; i < 4; ++i) {
                *(bf16x4*)th[i] = *(const bf16x4*)(BH + (size_t)(kk + kg * 4 + i) * 4096 + bn + cg);
                *(bf16x4*)tl[i] = *(const bf16x4*)(BL + (size_t)(kk + kg * 4 + i) * 4096 + bn + cg);
            }
#pragma unroll
            for (int j = 0; j < 4; ++j) {
                int r = (tid & 3) * 4 + j;
                int off = qsub * 512 + koff + ((r ^ qsub) & 15) * 8;
                short wh[4] = {th[0][j], th[1][j], th[2][j], th[3][j]};
                short wl[4] = {tl[0][j], tl[1][j], tl[2][j], tl[3][j]};
                *(bf16x4*)&Bhs[off] = *(bf16x4*)wh;
                *(bf16x4*)&Bls[off] = *(bf16x4*)wl;
            }
        }
        __syncthreads();

        bf16x8 af[2], bhf[4], blf[4];
#pragma unroll
        for (int m = 0; m < 2; ++m)
            af[m] = *(bf16x8*)&As[((wv >> 1) * 2 + m) * 512 + lane * 8];
#pragma unroll
        for (int n = 0; n < 4; ++n) {
            int sn = (wv & 1) * 4 + n;
            int boff = btm ? sn * 512 + lane * 8
                           : sn * 512 + l4 * 128 + ((l15 ^ sn) & 15) * 8;
            bhf[n] = *(bf16x8*)&Bhs[boff];
            blf[n] = *(bf16x8*)&Bls[boff];
        }
#pragma unroll
        for (int m = 0; m < 2; ++m)
#pragma unroll
            for (int n = 0; n < 4; ++n) {
                acc[m][n] = __builtin_amdgcn_mfma_f32_16x16x32_bf16(af[m], bhf[n], acc[m][n], 0, 0, 0);
                acc[m][n] = __builtin_amdgcn_mfma_f32_16x16x32_bf16(af[m], blf[n], acc[m][n], 0, 0, 0);
            }
        __syncthreads();
    }

    // ---- fused sampling epilogue ----
#pragma unroll
    for (int m = 0; m < 2; ++m)
#pragma unroll
        for (int n = 0; n < 4; ++n)
#pragma unroll
            for (int r = 0; r < 4; ++r) {
                int row = bm + wr + m * 16 + l4 * 4 + r;
                int col = bn + wc + n * 16 + l15;
                float val = acc[m][n][r];
                if (EPI == 2) {
                    if (col & 1) {
                        int s = (col - 1) >> 1;
                        uint32_t e = (uint32_t)(row * 2048 + s);
                        float p = sigmoidf_(val + bias[col]);
                        float u = tf_uniform01(rk0, rk1, e);
                        O0[(size_t)row * 4096 + col] = (u < p) ? (short)0x3F80 : (short)0;
                    } else {
                        O0[(size_t)row * 4096 + col] =
                            (occ[(size_t)row * 2048 + (col >> 1)] != 0.0f) ? (short)0x3F80 : (short)0;
                    }
                } else {
                    size_t e = (size_t)row * 4096 + col;
                    float p = sigmoidf_(val + bias[col]);
                    float u = tf_uniform01(rk0, rk1, (uint32_t)e);
                    short sv = (u < p) ? (short)0x3F80 : (short)0;
                    O0[e] = sv;
                    if (EPI == 1) O1[e] = sv;
                }
            }
}

// =====================================================================
// Gradient GEMM (exact): Out[i,j] = (sum_b Xn Yn - Xp Yp)/1024
// K-concat 64 steps of 32 b (neg 32, pos 32; pos-Y sign-negated).
// Same fragment-order subtiles with (r ^ subtile) swizzle; reg double-buffer.
// tile 128x128, 256 threads = 4 waves (64x64 each)
// =====================================================================
template<int W1MODE>
__global__ __launch_bounds__(256) void grad_mm(
    const short* __restrict__ Xn, const short* __restrict__ Yn,
    const short* __restrict__ Xp, const short* __restrict__ Yp_bf,
    const float* __restrict__ Yp_f32,
    float* __restrict__ Out)
{
    __shared__ __align__(1024) short Xs[2][8 * 512];
    __shared__ __align__(1024) short Ys[2][8 * 512];

    const int tid = threadIdx.x;
    const int bi = blockIdx.y * 128, bj = blockIdx.x * 128;
    const int wv = tid >> 6, lane = tid & 63;
    const int wr = (wv >> 1) * 64, wc = (wv & 1) * 64;
    const int l15 = lane & 15, l4 = lane >> 4;

    const int cg = (tid & 31) * 4;
    const int kg = tid >> 5;
    const int qsub = (tid & 31) >> 2;
    const int koff = (kg >> 1) * 128 + (kg & 1) * 4;

    f32x4 acc[4][4] = {};
    short xr[4][4];   // xr[i][j]: batch kg*4+i, col cg+j
    short yr[4][4];

    auto loadT = [&](int bt) {
        const bool neg = bt < 32;
        const int b0 = (bt & 31) * 32;
        const short* X = neg ? Xn : Xp;
#pragma unroll
        for (int i = 0; i < 4; ++i)
            *(bf16x4*)xr[i] = *(const bf16x4*)(X + (size_t)(b0 + kg * 4 + i) * NH + bi + cg);
        if (W1MODE) {
            if (neg) {
#pragma unroll
                for (int i = 0; i < 4; ++i) {
                    bf16x8 v = *(const bf16x8*)(Yn + (size_t)(b0 + kg * 4 + i) * NV + 2 * (bj + cg));
                    yr[i][0] = v[1]; yr[i][1] = v[3]; yr[i][2] = v[5]; yr[i][3] = v[7];
                }
            } else {
#pragma unroll
                for (int i = 0; i < 4; ++i) {
                    const float* p = Yp_f32 + (size_t)(b0 + kg * 4 + i) * NV + 2 * (bj + cg);
                    f32x4 a = *(const f32x4*)p;
                    f32x4 b = *(const f32x4*)(p + 4);
                    yr[i][0] = f2bf_trunc(-a[1]); yr[i][1] = f2bf_trunc(-a[3]);
                    yr[i][2] = f2bf_trunc(-b[1]); yr[i][3] = f2bf_trunc(-b[3]);
                }
            }
        } else {
            const short* Y = neg ? Yn : Yp_bf;
            const short sx = neg ? (short)0 : (short)0x8000;
#pragma unroll
            for (int i = 0; i < 4; ++i) {
                bf16x4 v = *(const bf16x4*)(Y + (size_t)(b0 + kg * 4 + i) * NH + bj + cg);
#pragma unroll
                for (int j = 0; j < 4; ++j) yr[i][j] = (short)(v[j] ^ sx);
            }
        }
    };
    auto writeT = [&](int buf) {
#pragma unroll
        for (int j = 0; j < 4; ++j) {
            int r = (tid & 3) * 4 + j;
            int off = qsub * 512 + koff + ((r ^ qsub) & 15) * 8;
            short wx[4] = {xr[0][j], xr[1][j], xr[2][j], xr[3][j]};
            short wy[4] = {yr[0][j], yr[1][j], yr[2][j], yr[3][j]};
            *(bf16x4*)&Xs[buf][off] = *(bf16x4*)wx;
            *(bf16x4*)&Ys[buf][off] = *(bf16x4*)wy;
        }
    };

    loadT(0);
    writeT(0);
    __syncthreads();

    for (int bt = 0; bt < 64; ++bt) {
        const int cur = bt & 1;
        if (bt + 1 < 64) loadT(bt + 1);

        bf16x8 xf[4], yf[4];
#pragma unroll
        for (int m = 0; m < 4; ++m) {
            int sm = (wv >> 1) * 4 + m;
            xf[m] = *(bf16x8*)&Xs[cur][sm * 512 + l4 * 128 + ((l15 ^ sm) & 15) * 8];
        }
#pragma unroll
        for (int n = 0; n < 4; ++n) {
            int sn = (wv & 1) * 4 + n;
            yf[n] = *(bf16x8*)&Ys[cur][sn * 512 + l4 * 128 + ((l15 ^ sn) & 15) * 8];
        }
#pragma unroll
        for (int m = 0; m < 4; ++m)
#pragma unroll
            for (int n = 0; n < 4; ++n)
                acc[m][n] = __builtin_amdgcn_mfma_f32_16x16x32_bf16(xf[m], yf[n], acc[m][n], 0, 0, 0);

        if (bt + 1 < 64) writeT(cur ^ 1);
        __syncthreads();
    }

    const float invB = 1.0f / 1024.0f;
#pragma unroll
    for (int m = 0; m < 4; ++m)
#pragma unroll
        for (int n = 0; n < 4; ++n)
#pragma unroll
            for (int r = 0; r < 4; ++r) {
                int i_ = bi + wr + m * 16 + l4 * 4 + r;
                int j_ = bj + wc + n * 16 + l15;
                if (W1MODE) {
                    Out[(size_t)i_ * NV + 2 * j_ + 1] = acc[m][n][r] * invB;
                    Out[(size_t)i_ * NV + 2 * j_]     = 0.0f;
                } else {
                    Out[(size_t)i_ * NH + j_] = acc[m][n][r] * invB;
                }
            }
}

// ---------------- small kernels ----------------
__global__ void cvt_kernel(const float* __restrict__ in, short* __restrict__ out, int n)
{
    int e = blockIdx.x * 256 + threadIdx.x;
    if (e < n) out[e] = (in[e] != 0.0f) ? (short)0x3F80 : (short)0;
}

__global__ void dbv_fast(const float* __restrict__ vdata, const short* __restrict__ vneg,
                         float* __restrict__ out)
{
    __shared__ float part[4][64];
    int c = threadIdx.x & 63, rg = threadIdx.x >> 6;
    int s = blockIdx.x * 64 + c;
    float acc = 0.0f;
    for (int b = rg; b < B_SZ; b += 4)
        acc += bf2f(vneg[(size_t)b * NV + 2 * s + 1]) - vdata[(size_t)b * NV + 2 * s + 1];
    part[rg][c] = acc;
    __syncthreads();
    if (rg == 0) {
        out[2 * s + 1] = (part[0][c] + part[1][c] + part[2][c] + part[3][c]) * (1.0f / 1024.0f);
        out[2 * s] = 0.0f;
    }
}

__global__ void dbh_fast(const short* __restrict__ Xp, const short* __restrict__ Xn,
                         float* __restrict__ out)
{
    __shared__ int part[4][64];
    int c = threadIdx.x & 63, rg = threadIdx.x >> 6;
    int j = blockIdx.x * 64 + c;
    int acc = 0;
    for (int b = rg; b < B_SZ; b += 4)
        acc += (int)(Xn[(size_t)b * NH + j] != 0) - (int)(Xp[(size_t)b * NH + j] != 0);
    part[rg][c] = acc;
    __syncthreads();
    if (rg == 0)
        out[j] = (float)(part[0][c] + part[1][c] + part[2][c] + part[3][c]) * (1.0f / 1024.0f);
}

__global__ void zero_kernel(unsigned* p) { *p = 0u; }

__global__ void loss_count2(const float* __restrict__ vdata,
                            const short* __restrict__ vneg, unsigned* cnt)
{
    __shared__ int part[4];
    int t = blockIdx.x * 256 + threadIdx.x;
    int local = 0;
#pragma unroll
    for (int it = 0; it < 8; ++it) {
        int e = t + it * 262144;
        int b = e >> 11, s = e & 2047;
        float st = vdata[(size_t)b * NV + 2 * s + 1];
        float sp = bf2f(vneg[(size_t)b * NV + 2 * s + 1]);
        local += (st != sp) ? 1 : 0;
    }
#pragma unroll
    for (int off = 32; off; off >>= 1) local += __shfl_down(local, off, 64);
    if ((threadIdx.x & 63) == 0) part[threadIdx.x >> 6] = local;
    __syncthreads();
    if (threadIdx.x == 0)
        atomicAdd(cnt, (unsigned)(part[0] + part[1] + part[2] + part[3]));
}

__global__ void loss_final_kernel(const unsigned* cnt, float* out, float lp, float lm)
{
    float mis = (float)(*cnt);
    float mat = 2097152.0f - mis;
    out[0] = -((mat * lp + mis * lm) * (1.0f / 2097152.0f));
}

// ---------------- host ----------------
extern "C" void kernel_launch(void* const* d_in, const int* in_sizes, int n_in,
                              void* d_out, int out_size, void* d_ws, size_t ws_size,
                              hipStream_t stream)
{
    (void)in_sizes; (void)n_in; (void)out_size; (void)ws_size;
    const float* v_data = (const float*)d_in[0];
    const float* occ    = (const float*)d_in[1];
    const float* W1     = (const float*)d_in[2];
    const float* b_v    = (const float*)d_in[3];
    const float* b_h1   = (const float*)d_in[4];
    const float* W2     = (const float*)d_in[5];
    const float* b_h2   = (const float*)d_in[6];
    float* out = (float*)d_out;

    char* w = (char*)d_ws;
    short* vneg = (short*)w;
    short* h1d  = vneg + (size_t)B_SZ * NV;
    short* h2d  = h1d  + (size_t)B_SZ * NH;
    short* h1c  = h2d  + (size_t)B_SZ * NH;
    short* h2n  = h1c  + (size_t)B_SZ * NH;
    unsigned* cnt = (unsigned*)(h2n + (size_t)B_SZ * NH);

    // d_out doubles as weight scratch during the forward phase.
    short* W1h = (short*)(((uintptr_t)(out + 1) + 15) & ~(uintptr_t)15);
    short* W1l = W1h + (size_t)NH * NV;
    short* W2h = W1l + (size_t)NH * NV;
    short* W2l = W2h + (size_t)NH * NH;

    // ---- JAX key derivation ----
    const uint32_t r0 = 0u, r1 = 42u;
    uint32_t kp1a, kp1b, kp2a, kp2b, kfa, kfb, kla, klb;
    tf2x32(r0, r1, 0u, 0u, kp1a, kp1b);
    tf2x32(r0, r1, 0u, 1u, kp2a, kp2b);
    tf2x32(r0, r1, 0u, 2u, kfa, kfb);
    tf2x32(r0, r1, 0u, 3u, kla, klb);
    uint32_t kaA[2], kaB[2], kbA[2], kbB[2], kcA[2], kcB[2];
    for (int i = 0; i < 2; ++i) {
        uint32_t fa, fb;
        tf2x32(kla, klb, 0u, (uint32_t)i, fa, fb);
        tf2x32(fa, fb, 0u, 0u, kaA[i], kaB[i]);
        tf2x32(fa, fb, 0u, 1u, kbA[i], kbB[i]);
        tf2x32(fa, fb, 0u, 2u, kcA[i], kcB[i]);
    }

    const int T = 256;
    const int NELEM = B_SZ * NH;
    dim3 gMM(NV / 128, B_SZ / 64);     // 32 x 16 = 512 blocks

    conv_bt<<<(NH * NV) / (4 * 256), 256, 0, stream>>>(W1, W1h, W1l);
    conv_bt<<<(NH * NH) / (4 * 256), 256, 0, stream>>>(W2, W2h, W2l);

    cvt_kernel<<<NELEM / T, T, 0, stream>>>(v_data, vneg, NELEM);

    // positive phase
    mm_fast<0, 0><<<gMM, 256, 0, stream>>>(vneg, nullptr, W1h, W1l, nullptr, nullptr,
                                           b_h1, nullptr, h1d, nullptr, kp1a, kp1b);
    mm_fast<1, 0><<<gMM, 256, 0, stream>>>(h1d, nullptr, W2h, W2l, nullptr, nullptr,
                                           b_h2, nullptr, h2d, h2n, kp2a, kp2b);

    // Gibbs loop (k = 2)
    for (int i = 0; i < 2; ++i) {
        mm_fast<0, 1><<<gMM, 256, 0, stream>>>(vneg, h2n, W1h, W1l, W2h, W2l,
                                               b_h1, nullptr, h1c, nullptr, kaA[i], kaB[i]);
        mm_fast<0, 0><<<gMM, 256, 0, stream>>>(h1c, nullptr, W2h, W2l, nullptr, nullptr,
                                               b_h2, nullptr, h2n, nullptr, kbA[i], kbB[i]);
        mm_fast<2, 2><<<gMM, 256, 0, stream>>>(h1c, nullptr, W1h, W1l, nullptr, nullptr,
                                               b_v, occ, vneg, nullptr, kcA[i], kcB[i]);
    }

    // final hidden refresh
    mm_fast<0, 1><<<gMM, 256, 0, stream>>>(vneg, h2n, W1h, W1l, W2h, W2l,
                                           b_h1, nullptr, h1c, nullptr, kfa, kfb);

    // outputs (weight scratch dead after this point)
    float* dW1o  = out + 1;
    float* dbvo  = dW1o + (size_t)NH * NV;
    float* dbh1o = dbvo + NV;
    float* dW2o  = dbh1o + NH;
    float* dbh2o = dW2o + (size_t)NH * NH;

    grad_mm<1><<<dim3(NSGN / 128, NH / 128), T, 0, stream>>>(h1c, vneg, h1d, (short*)nullptr, v_data, dW1o);
    grad_mm<0><<<dim3(NH / 128, NH / 128), T, 0, stream>>>(h1c, h2n, h1d, h2d, (const float*)nullptr, dW2o);
    dbv_fast<<<NSGN / 64, T, 0, stream>>>(v_data, vneg, dbvo);
    dbh_fast<<<NH / 64, T, 0, stream>>>(h1d, h1c, dbh1o);
    dbh_fast<<<NH / 64, T, 0, stream>>>(h2d, h2n, dbh2o);

    zero_kernel<<<1, 1, 0, stream>>>(cnt);
    loss_count2<<<1024, T, 0, stream>>>(v_data, vneg, cnt);
    loss_final_kernel<<<1, 1, 0, stream>>>(cnt, out, logf(1.0f + 1e-7f), logf(1e-7f));
}